// Round 5
// baseline (129.201 us; speedup 1.0000x reference)
//
#include <hip/hip_runtime.h>

// filtfilt butter(4,0.2), 512 rows x T=32768 fp32.  R9: R7 + two generations.
//  - R8 post-mortem: intra-wave A/B pipeline halved waves to 16/CU -> regressed
//    (42.6 vs ~38us). Lesson: this kernel's currency is TLP, not in-wave ILP.
//  - R9: R7 per-segment structure verbatim, but kSeg 2048 -> 1024 (chunk 16/lane).
//    16384 waves = 64/CU worth = TWO generations: gen-2 waves issue loads while
//    gen-1 computes/stores -> load/compute/store overlap across generations,
//    which R7's single lockstep generation structurally lacked. Per-wave serial
//    span drops 152 -> 120 STEP-slots. Compute/output +58% (~8us total VALU),
//    still below the ~16us memory floor.
//  - fp16 LDS slice [pre32 | 1024 | post32] = 2176B; XOR swizzle ((lo>>7)&7)<<4
//    (identity in pre [0,64) and post [2112,2176)). Y over X in place; bwd
//    warm-up 28 reads neighbor lanes' Y (chunks l+1,l+2); lane-63 seam builds W.
//  - exact odd-ext at both signal ends (R7 paths, chunk-16 indexing).
//  - launch_bounds(256,8): VGPR cap 64 (expected ~50; R8 measured 48 with MORE
//    state). Spill tell = WRITE_SIZE >> 66MB. LDS 8704B/block, 8 blocks/CU.

typedef __fp16 h4 __attribute__((ext_vector_type(4)));
typedef __fp16 h8 __attribute__((ext_vector_type(8)));

constexpr int kT      = 32768;
constexpr int kSeg    = 1024;          // samples per wave
constexpr int kNSeg   = kT / kSeg;     // 32 segments/row
constexpr int kTPB    = 256;           // 4 waves / block
constexpr int kSliceB = 2176;          // 64B pre + 2048B main + 64B post

#define B0 0.0048243445989025905f
#define B1 0.019297378395610362f
#define B2 0.028946067593415543f
#define B3 0.019297378395610362f
#define B4 0.0048243445989025905f
#define NA1 2.369513007182038f
#define NA2 (-2.3139884144002064f)
#define NA3 1.0546654058785661f
#define NA4 (-0.18737949236818502f)

#define STEPF(xv) do { \
    y  = fmaf(B0, (xv), z1); \
    z1 = fmaf(NA1, y, fmaf(B1, (xv), z2)); \
    z2 = fmaf(NA2, y, fmaf(B2, (xv), z3)); \
    z3 = fmaf(NA3, y, fmaf(B3, (xv), z4)); \
    z4 = fmaf(NA4, y, B4 * (xv)); \
} while (0)

#define PK(a, b) __builtin_bit_cast(int, __builtin_amdgcn_cvt_pkrtz((a), (b)))

__device__ __forceinline__ int swz(int lo) { return lo ^ (((lo >> 7) & 7) << 4); }

__global__ __launch_bounds__(kTPB, 8)
void filtfilt_kernel(const float* __restrict__ x, float* __restrict__ out) {
    __shared__ __align__(16) char lds[4 * kSliceB];
    const int t  = threadIdx.x;
    const int l  = t & 63;                       // lane == chunk index (16 samples)
    const int wv = t >> 6;
    const int W  = blockIdx.x * 4 + wv;
    const int row = W >> 5;                      // 32 segs/row
    const int seg = W & (kNSeg - 1);
    const float* __restrict__ xr   = x   + (size_t)row * kT + seg * kSeg;
    float* __restrict__ outr       = out + (size_t)row * kT + seg * kSeg;
    char* Lb = lds + wv * kSliceB;
    const bool haspre  = (seg > 0);
    const bool haspost = (seg < kNSeg - 1);

    // ================= stage: coalesced global -> fp16 LDS =================
    const float4* xp = (const float4*)xr;
    float4 mv[4];
    #pragma unroll
    for (int i = 0; i < 4; ++i) mv[i] = xp[i * 64 + l];
    float4 pre4 = {0.f, 0.f, 0.f, 0.f}, post4 = {0.f, 0.f, 0.f, 0.f};
    if (l < 8) {
        if (haspre)  pre4  = *(const float4*)(xr - 32 + l * 4);
        if (haspost) post4 = *(const float4*)(xr + kSeg + l * 4);
    }
    #pragma unroll
    for (int i = 0; i < 4; ++i) {
        int lo = swz(64 + i * 512 + 8 * l);
        int2 wi = { PK(mv[i].x, mv[i].y), PK(mv[i].z, mv[i].w) };
        *(int2*)(Lb + lo) = wi;
    }
    if (l < 8) {
        if (haspre) {                            // pre slot: x[sb-32, sb)
            int2 wi = { PK(pre4.x, pre4.y), PK(pre4.z, pre4.w) };
            *(int2*)(Lb + 8 * l) = wi;           // [0,64): identity under swz
        }
        if (haspost) {                           // post slot: x[sb+1024, +32)
            int2 wi = { PK(post4.x, post4.y), PK(post4.z, post4.w) };
            *(int2*)(Lb + 2112 + 8 * l) = wi;    // identity under swz
        }
    }
    asm volatile("s_waitcnt lgkmcnt(0)" ::: "memory");
    if (!haspre && l < 8) {
        // seg 0: pre = 17 zeros + 15 left odd-ext (exact; zero-IC-preserving pad)
        const __fp16* xs = (const __fp16*)(Lb + 64);   // samples 0..31, identity
        float x0 = (float)xs[0];
        float v[4];
        #pragma unroll
        for (int r = 0; r < 4; ++r) {
            int k = 4 * l + r;
            v[r] = (k < 17) ? 0.f : fmaf(2.f, x0, -(float)xs[32 - k]);
        }
        int2 wi = { PK(v[0], v[1]), PK(v[2], v[3]) };
        *(int2*)(Lb + 8 * l) = wi;
    }
    asm volatile("" ::: "memory");

    // ================= phase 1: fwd warm-up (32 samples before chunk) ======
    float z1 = 0.f, z2 = 0.f, z3 = 0.f, z4 = 0.f, y;
    {
        const int wb = 32 * l;                   // byte of sample 16l-32
        #pragma unroll
        for (int j = 0; j < 4; ++j) {
            h8 v = *(const h8*)(Lb + swz(wb + 16 * j));
            #pragma unroll
            for (int e = 0; e < 8; ++e) STEPF((float)v[e]);
        }
    }

    // ================= phase 2: fwd main (16), Y over X in place ===========
    h8 tailA, tailB;    // raw X of own chunk (for last-seg right ext)
    {
        const int mb = 64 + 32 * l;
        #pragma unroll
        for (int j = 0; j < 2; ++j) {
            char* p = Lb + swz(mb + 16 * j);
            h8 v = *(const h8*)p;
            if (j == 0) tailA = v;
            else        tailB = v;
            float q[8];
            #pragma unroll
            for (int e = 0; e < 8; ++e) { STEPF((float)v[e]); q[e] = y; }
            int4 wi = { PK(q[0], q[1]), PK(q[2], q[3]), PK(q[4], q[5]), PK(q[6], q[7]) };
            *(int4*)p = wi;
        }
    }

    // ====== phase 2.5 (lane 63 only): build W into post region =============
    if (l == 63) {
        if (haspost) {
            // continue fwd chain over post X (28 steps), write y -> post
            #pragma unroll
            for (int g = 0; g < 4; ++g) {
                h8 v = *(const h8*)(Lb + 2112 + 16 * g);
                if (g < 3) {
                    float q[8];
                    #pragma unroll
                    for (int e = 0; e < 8; ++e) { STEPF((float)v[e]); q[e] = y; }
                    int4 wi = { PK(q[0], q[1]), PK(q[2], q[3]), PK(q[4], q[5]), PK(q[6], q[7]) };
                    *(int4*)(Lb + 2112 + 16 * g) = wi;
                } else {
                    float q[4];
                    #pragma unroll
                    for (int e = 0; e < 4; ++e) { STEPF((float)v[e]); q[e] = y; }
                    int4 wi = { PK(q[0], q[1]), PK(q[2], q[3]), 0, 0 };
                    *(int4*)(Lb + 2112 + 16 * g) = wi;
                }
            }
        } else {
            // last seg: 15 exact right odd-ext y (continue chain), zero-padded
            float xl = (float)tailB[7];
            float q[8];
            #pragma unroll
            for (int j = 0; j < 8; ++j) {
                float xe = fmaf(2.f, xl, -(float)(j < 7 ? tailB[6 - j] : tailA[14 - j]));
                STEPF(xe); q[j] = y;
            }
            int4 w0 = { PK(q[0], q[1]), PK(q[2], q[3]), PK(q[4], q[5]), PK(q[6], q[7]) };
            *(int4*)(Lb + 2112) = w0;
            float r[7];
            #pragma unroll
            for (int j = 8; j < 15; ++j) {
                float xe = fmaf(2.f, xl, -(float)tailA[14 - j]);
                STEPF(xe); r[j - 8] = y;
            }
            int4 w1 = { PK(r[0], r[1]), PK(r[2], r[3]), PK(r[4], r[5]), PK(r[6], 0.f) };
            *(int4*)(Lb + 2128) = w1;
            int4 zz = {0, 0, 0, 0};
            *(int4*)(Lb + 2144) = zz;
            *(int4*)(Lb + 2160) = zz;
        }
    }
    asm volatile("" ::: "memory");

    // ====== phase 3: bwd warm-up (28, chunks l+1,l+2 Y / post W, desc) =====
    z1 = z2 = z3 = z4 = 0.f;
    {
        const int bb = 64 + 32 * (l + 1);
        h8 w3v = *(const h8*)(Lb + swz(bb + 48));
        h8 w2v = *(const h8*)(Lb + swz(bb + 32));
        h8 w1v = *(const h8*)(Lb + swz(bb + 16));
        h8 w0v = *(const h8*)(Lb + swz(bb +  0));
        STEPF((float)w3v[3]); STEPF((float)w3v[2]);
        STEPF((float)w3v[1]); STEPF((float)w3v[0]);
        #pragma unroll
        for (int e = 7; e >= 0; --e) STEPF((float)w2v[e]);
        #pragma unroll
        for (int e = 7; e >= 0; --e) STEPF((float)w1v[e]);
        #pragma unroll
        for (int e = 7; e >= 0; --e) STEPF((float)w0v[e]);
    }

    // ====== phase 4: bwd main (16, descending), out over Y in place ========
    {
        const int mb = 64 + 32 * l;
        #pragma unroll
        for (int j = 1; j >= 0; --j) {
            char* p = Lb + swz(mb + 16 * j);
            h8 v = *(const h8*)p;
            float q[8];
            #pragma unroll
            for (int e = 7; e >= 0; --e) { STEPF((float)v[e]); q[e] = y; }
            int4 wi = { PK(q[0], q[1]), PK(q[2], q[3]), PK(q[4], q[5]), PK(q[6], q[7]) };
            *(int4*)p = wi;
        }
    }
    asm volatile("" ::: "memory");

    // ================= phase 5: coalesced fp16 LDS -> fp32 global ==========
    float4* op = (float4*)outr;
    #pragma unroll
    for (int i = 0; i < 4; ++i) {
        int lo = swz(64 + i * 512 + 8 * l);
        h4 hv = *(const h4*)(Lb + lo);
        float4 o = { (float)hv[0], (float)hv[1], (float)hv[2], (float)hv[3] };
        op[i * 64 + l] = o;
    }
}

extern "C" void kernel_launch(void* const* d_in, const int* in_sizes, int n_in,
                              void* d_out, int out_size, void* d_ws, size_t ws_size,
                              hipStream_t stream) {
    const float* x = (const float*)d_in[0];
    float* outp    = (float*)d_out;
    const int rows   = in_sizes[0] / kT;                  // 512
    const int blocks = rows * kNSeg * 64 / kTPB;          // 4096
    filtfilt_kernel<<<blocks, kTPB, 0, stream>>>(x, outp);
}